// Round 3
// baseline (159.013 us; speedup 1.0000x reference)
//
#include <hip/hip_runtime.h>
#include <math.h>

#define NB  32
#define NKC 128
#define DH  64
#define NEX 1024
#define G3  192

// ws layout (floats)
#define KCIOFF  0         // 32*128  = 4096
#define EPOFF   4096      // 128*64  = 8192
#define NHOFF   12288     // 32*128*64 = 262144
#define DPOFF   274432    // 32*128*64 = 262144  (end = 536576 floats = 2.15 MB)

__device__ __forceinline__ float sigf(float x) { return 1.0f / (1.0f + expf(-x)); }

// ---------------------------------------------------------------------------
// kA: x (local recompute) + kci slice + tgru cell + new_h + dpart; blocks 0-3
// additionally compute epart. grid = 128 blocks (b x 4 i-chunks of 32).
// ---------------------------------------------------------------------------
__global__ __launch_bounds__(256) void kA_tgru(
    const float* __restrict__ h, const float* __restrict__ ex,
    const float* __restrict__ su, const float* __restrict__ ex_graph,
    const float* __restrict__ W_ex, const float* __restrict__ W_kc,
    const float* __restrict__ tgru_wih, const float* __restrict__ tgru_whh,
    const float* __restrict__ tgru_bih, const float* __restrict__ tgru_bhh,
    const float* __restrict__ fpart_w, const float* __restrict__ fpart_b,
    float* __restrict__ ws)
{
    int t = threadIdx.x, wave = t >> 6, lane = t & 63;
    int b = blockIdx.x >> 2;
    int i0 = (blockIdx.x & 3) * 32;

    __shared__ float exs[NEX];
    __shared__ float whhT[32 * 193];   // reused: fpart_w^T (64*65), epart fwT
    __shared__ float wihT[32 * 193];   // reused: epart wkS
    __shared__ float ht[32 * DH];
    __shared__ float dlt[32 * DH];
    __shared__ float xs[DH];
    __shared__ float bih3[G3];
    __shared__ float bhh3[G3];
    __shared__ float kred[256];
    __shared__ float kcis[32];

    // stage ex[b] (float4) and h tile
    {
        int idx = t * 4;
        *(float4*)&exs[idx] = *(const float4*)&ex[(size_t)b * NEX + idx];
    }
    const float* hb = h + (size_t)(b * NKC + i0) * DH;
    for (int idx = t; idx < 32 * DH; idx += 256) ht[idx] = hb[idx];
    if (t < G3) { bih3[t] = tgru_bih[t]; bhh3[t] = tgru_bhh[t]; }
    __syncthreads();

    // x[b,d] = su*dot(ex, W_ex[d,:1024]) + (1-su)*dot(ex, W_ex[d,1024:])
    float sub = su[b];
    for (int m = 0; m < 16; ++m) {
        int d = wave * 16 + m;
        const float* wr = W_ex + (size_t)d * (2 * NEX);
        float a1 = 0.f, a2 = 0.f;
        #pragma unroll
        for (int i = 0; i < 16; ++i) {
            int k = lane + i * 64;
            a1 = fmaf(exs[k], wr[k], a1);
            a2 = fmaf(exs[k], wr[NEX + k], a2);
        }
        float v = sub * a1 + (1.0f - sub) * a2;
        #pragma unroll
        for (int off = 32; off; off >>= 1) v += __shfl_down(v, off, 64);
        if (lane == 0) xs[d] = v;
    }
    // kci[b, i0+i] partials: i = t&31, k-slice = t>>5 (128 k each)
    {
        int i = t & 31, ks = t >> 5;
        const float* eg = ex_graph + i0 + i;
        int kb = ks * 128;
        float a = 0.f;
        for (int k = 0; k < 128; ++k)
            a = fmaf(exs[kb + k], eg[(size_t)(kb + k) * NKC], a);
        kred[t] = a;
    }
    __syncthreads();   // xs + kred ready
    if (t < 32) {
        float s = 0.f;
        #pragma unroll
        for (int r = 0; r < 8; ++r) s += kred[r * 32 + t];
        kcis[t] = s;
        ws[KCIOFF + b * NKC + i0 + t] = s;
    }

    float gir = bih3[lane], giz = bih3[64 + lane], gin = bih3[128 + lane];
    float ar[8], az[8], an[8];
    #pragma unroll
    for (int m = 0; m < 8; ++m) {
        ar[m] = bhh3[lane]; az[m] = bhh3[64 + lane]; an[m] = bhh3[128 + lane];
    }

    for (int ch = 0; ch < 2; ++ch) {
        __syncthreads();
        for (int idx = t; idx < G3 * 32; idx += 256) {
            int row = idx >> 5, kk = idx & 31;
            whhT[kk * 193 + row] = tgru_whh[row * DH + ch * 32 + kk];
            wihT[kk * 193 + row] = tgru_wih[row * DH + ch * 32 + kk];
        }
        __syncthreads();
        for (int kk = 0; kk < 32; ++kk) {
            float wr = whhT[kk * 193 + lane];
            float wz = whhT[kk * 193 + 64 + lane];
            float wn = whhT[kk * 193 + 128 + lane];
            float xk = xs[ch * 32 + kk];
            gir = fmaf(wihT[kk * 193 + lane], xk, gir);
            giz = fmaf(wihT[kk * 193 + 64 + lane], xk, giz);
            gin = fmaf(wihT[kk * 193 + 128 + lane], xk, gin);
            int k = ch * 32 + kk;
            #pragma unroll
            for (int m = 0; m < 8; ++m) {
                float hk = ht[(wave * 8 + m) * DH + k];   // LDS broadcast
                ar[m] = fmaf(wr, hk, ar[m]);
                az[m] = fmaf(wz, hk, az[m]);
                an[m] = fmaf(wn, hk, an[m]);
            }
        }
    }
    // GRU epilogue per i
    #pragma unroll
    for (int m = 0; m < 8; ++m) {
        int il = wave * 8 + m;
        float hval = ht[il * DH + lane];
        float r = sigf(gir + ar[m]);
        float z = sigf(giz + az[m]);
        float n = tanhf(gin + r * an[m]);
        float th = (1.0f - z) * n + z * hval;
        float kv = kcis[il];
        float nh = (1.0f - kv) * hval + kv * th;
        ws[NHOFF + (size_t)(b * NKC + i0 + il) * DH + lane] = nh;
        dlt[il * DH + lane] = kv * (th - hval);   // delta_h
    }
    __syncthreads();
    // dpart = delta_h @ fpart_w[:, :64].T ; stage fpart_w^T (stride 65)
    for (int idx = t; idx < 4096; idx += 256) {
        int d = idx >> 6, k = idx & 63;
        whhT[k * 65 + d] = fpart_w[d * 128 + k];
    }
    __syncthreads();
    float acc[8];
    #pragma unroll
    for (int m = 0; m < 8; ++m) acc[m] = 0.f;
    for (int k = 0; k < 64; ++k) {
        float w = whhT[k * 65 + lane];
        #pragma unroll
        for (int m = 0; m < 8; ++m)
            acc[m] = fmaf(dlt[(wave * 8 + m) * DH + k], w, acc[m]);
    }
    #pragma unroll
    for (int m = 0; m < 8; ++m)
        ws[DPOFF + (size_t)(b * NKC + i0 + wave * 8 + m) * DH + lane] = acc[m];

    // blocks 0..3: epart[j,d] = sum_c W_kc[c,j]*fpart_w[d,64+c] + fpart_b[d]
    if (blockIdx.x < 4) {
        int eb = blockIdx.x;
        __syncthreads();
        float* fwT = whhT;            // 64*65 = 4160 floats
        float* wkS = wihT;            // 64*33 = 2112 floats
        for (int idx = t; idx < 4096; idx += 256) {
            int d = idx >> 6, c = idx & 63;
            fwT[c * 65 + d] = fpart_w[d * 128 + 64 + c];
        }
        for (int idx = t; idx < 2048; idx += 256) {
            int c = idx >> 5, jl = idx & 31;
            wkS[c * 33 + jl] = W_kc[(size_t)c * NKC + eb * 32 + jl];
        }
        __syncthreads();
        float fb = fpart_b[lane];
        #pragma unroll
        for (int q2 = 0; q2 < 8; ++q2) {
            int jl = wave + 4 * q2;
            float a = fb;
            for (int c = 0; c < 64; ++c)
                a = fmaf(wkS[c * 33 + jl], fwT[c * 65 + lane], a);
            ws[EPOFF + (eb * 32 + jl) * DH + lane] = a;
        }
    }
}

// ---------------------------------------------------------------------------
// kB: partj + outj + kcj + ugru + h_out; kc_graph sigmoid folded into wj.
// grid = 256 blocks (b x 8 j-chunks of 16).
// ---------------------------------------------------------------------------
__global__ __launch_bounds__(256) void kB_update(
    const float* __restrict__ kc_gamma,
    const float* __restrict__ ulin_w, const float* __restrict__ ulin_b,
    const float* __restrict__ ugru_wih, const float* __restrict__ ugru_whh,
    const float* __restrict__ ugru_bih, const float* __restrict__ ugru_bhh,
    float* __restrict__ ws, float* __restrict__ out)
{
    int t = threadIdx.x, wave = t >> 6, lane = t & 63;
    int b = blockIdx.x >> 3;
    int j0 = (blockIdx.x & 7) * 16;

    __shared__ float scratch[12352];  // a: dpart|wj|ep; b: ulin^T; c: wih^T+whh^T
    __shared__ float pjS[16 * DH];
    __shared__ float outjS[16 * DH];
    __shared__ float newhS[16 * DH];
    __shared__ float kcis[NKC];
    __shared__ float kcjS[16];
    __shared__ float bihS[G3];
    __shared__ float bhhS[G3];

    float* dpartS = scratch;           // 8192  [i*64+d]
    float* wjS    = scratch + 8192;    // 2048  [i*16+jl]
    float* epS    = scratch + 10240;   // 1024  [jl*64+d]

    const float* dp = ws + DPOFF + (size_t)b * NKC * DH;
    for (int idx = t; idx < NKC * DH; idx += 256) dpartS[idx] = dp[idx];
    if (t < NKC) kcis[t] = ws[KCIOFF + b * NKC + t];
    for (int idx = t; idx < 16 * DH; idx += 256) {
        epS[idx]   = ws[EPOFF + j0 * DH + idx];
        newhS[idx] = ws[NHOFF + (size_t)(b * NKC + j0) * DH + idx];
    }
    if (t < G3) { bihS[t] = ugru_bih[t]; bhhS[t] = ugru_bhh[t]; }
    __syncthreads();
    // wj[i,jl] = kci[i] * sigmoid(kc_gamma[i, j0+jl])
    for (int idx = t; idx < 2048; idx += 256) {
        int i = idx >> 4, jl = idx & 15;
        wjS[idx] = kcis[i] * sigf(kc_gamma[i * NKC + j0 + jl]);
    }
    __syncthreads();
    if (t < 16) {  // kcj[jl] = sum_i wj[i,jl]
        float s = 0.f;
        for (int i = 0; i < NKC; ++i) s += wjS[i * 16 + t];
        kcjS[t] = s;
    }
    // phase a: partj — i-loop shared across 4 j per wave
    float ep[4], pa[4];
    #pragma unroll
    for (int q = 0; q < 4; ++q) { ep[q] = epS[(wave + 4 * q) * DH + lane]; pa[q] = 0.f; }
    for (int i = 0; i < NKC; ++i) {
        float dv = dpartS[i * DH + lane];
        #pragma unroll
        for (int q = 0; q < 4; ++q) {
            float pre = fmaxf(dv + ep[q], 0.f);
            pa[q] = fmaf(pre, wjS[i * 16 + wave + 4 * q], pa[q]);
        }
    }
    #pragma unroll
    for (int q = 0; q < 4; ++q) pjS[(wave + 4 * q) * DH + lane] = pa[q];
    __syncthreads();
    // phase b: outj = relu(partj @ ulin_w.T + b)
    float* ulT = scratch;  // 64*65
    for (int idx = t; idx < 4096; idx += 256) {
        int d2 = idx >> 6, k = idx & 63;
        ulT[k * 65 + d2] = ulin_w[d2 * DH + k];
    }
    float ulb = ulin_b[lane];
    __syncthreads();
    #pragma unroll
    for (int q = 0; q < 4; ++q) {
        int jl = wave + 4 * q;
        float a = ulb;
        for (int k = 0; k < DH; ++k) a = fmaf(pjS[jl * DH + k], ulT[k * 65 + lane], a);
        outjS[jl * DH + lane] = fmaxf(a, 0.f);
    }
    // phase c: ugru — both weight matrices k-chunk staged
    float* wihT = scratch;           // 32*193
    float* whhT = scratch + 6176;    // 32*193
    float gir[4], giz[4], gin[4], ghr[4], ghz[4], ghn[4];
    #pragma unroll
    for (int q = 0; q < 4; ++q) { gir[q] = giz[q] = gin[q] = ghr[q] = ghz[q] = ghn[q] = 0.f; }
    for (int ch = 0; ch < 2; ++ch) {
        __syncthreads();   // also covers phase-b reads of ulT before overwrite
        for (int idx = t; idx < G3 * 32; idx += 256) {
            int row = idx >> 5, kk = idx & 31;
            wihT[kk * 193 + row] = ugru_wih[row * DH + ch * 32 + kk];
            whhT[kk * 193 + row] = ugru_whh[row * DH + ch * 32 + kk];
        }
        __syncthreads();
        for (int kk = 0; kk < 32; ++kk) {
            float wir = wihT[kk * 193 + lane];
            float wiz = wihT[kk * 193 + 64 + lane];
            float win = wihT[kk * 193 + 128 + lane];
            float wwr = whhT[kk * 193 + lane];
            float wwz = whhT[kk * 193 + 64 + lane];
            float wwn = whhT[kk * 193 + 128 + lane];
            int k = ch * 32 + kk;
            #pragma unroll
            for (int q = 0; q < 4; ++q) {
                int jl = wave + 4 * q;
                float ov = outjS[jl * DH + k];
                float nv = newhS[jl * DH + k];
                gir[q] = fmaf(wir, ov, gir[q]);
                giz[q] = fmaf(wiz, ov, giz[q]);
                gin[q] = fmaf(win, ov, gin[q]);
                ghr[q] = fmaf(wwr, nv, ghr[q]);
                ghz[q] = fmaf(wwz, nv, ghz[q]);
                ghn[q] = fmaf(wwn, nv, ghn[q]);
            }
        }
    }
    #pragma unroll
    for (int q = 0; q < 4; ++q) {
        int jl = wave + 4 * q;
        float r = sigf(gir[q] + bihS[lane] + ghr[q] + bhhS[lane]);
        float z = sigf(giz[q] + bihS[64 + lane] + ghz[q] + bhhS[64 + lane]);
        float n = tanhf(gin[q] + bihS[128 + lane] + r * (ghn[q] + bhhS[128 + lane]));
        float nh = newhS[jl * DH + lane];
        float uh = (1.0f - z) * n + z * nh;
        float kj = kcjS[jl];
        out[(size_t)(b * NKC + j0 + jl) * DH + lane] = (1.0f - kj) * nh + kj * uh;
    }
}

extern "C" void kernel_launch(void* const* d_in, const int* in_sizes, int n_in,
                              void* d_out, int out_size, void* d_ws, size_t ws_size,
                              hipStream_t stream) {
    const float* h        = (const float*)d_in[0];
    const float* ex       = (const float*)d_in[1];
    const float* su       = (const float*)d_in[2];
    const float* ex_graph = (const float*)d_in[3];
    const float* kc_gamma = (const float*)d_in[4];
    const float* W_ex     = (const float*)d_in[5];
    const float* W_kc     = (const float*)d_in[6];
    const float* tgru_wih = (const float*)d_in[7];
    const float* tgru_whh = (const float*)d_in[8];
    const float* tgru_bih = (const float*)d_in[9];
    const float* tgru_bhh = (const float*)d_in[10];
    const float* fpart_w  = (const float*)d_in[11];
    const float* fpart_b  = (const float*)d_in[12];
    const float* ulin_w   = (const float*)d_in[13];
    const float* ulin_b   = (const float*)d_in[14];
    const float* ugru_wih = (const float*)d_in[15];
    const float* ugru_whh = (const float*)d_in[16];
    const float* ugru_bih = (const float*)d_in[17];
    const float* ugru_bhh = (const float*)d_in[18];
    float* ws  = (float*)d_ws;
    float* out = (float*)d_out;

    hipLaunchKernelGGL(kA_tgru, dim3(128), dim3(256), 0, stream,
                       h, ex, su, ex_graph, W_ex, W_kc,
                       tgru_wih, tgru_whh, tgru_bih, tgru_bhh,
                       fpart_w, fpart_b, ws);
    hipLaunchKernelGGL(kB_update, dim3(256), dim3(256), 0, stream,
                       kc_gamma, ulin_w, ulin_b,
                       ugru_wih, ugru_whh, ugru_bih, ugru_bhh, ws, out);
}

// Round 4
// 150.377 us; speedup vs baseline: 1.0574x; 1.0574x over previous
//
#include <hip/hip_runtime.h>
#include <math.h>

#define NB  32
#define NKC 128
#define DH  64
#define NEX 1024
#define G3  192

// ws layout (floats)
#define XOFF    0         // 32*64   = 2048
#define KCIOFF  2048      // 32*128  = 4096
#define EPOFF   6144      // 128*64  = 8192
#define NHOFF   14336     // 32*128*64 = 262144
#define DPOFF   276480    // 32*128*64 = 262144  (end = 538624 floats = 2.15 MB)

__device__ __forceinline__ float sigf(float x) { return 1.0f / (1.0f + expf(-x)); }

// ---------------------------------------------------------------------------
// k0: x (blocks 0..255), kci (256..511), epart (512..515). 256 threads.
// Short serial chains, ~2 blocks/CU for latency hiding.
// ---------------------------------------------------------------------------
__global__ __launch_bounds__(256) void k0_prep(
    const float* __restrict__ ex, const float* __restrict__ su,
    const float* __restrict__ ex_graph, const float* __restrict__ W_ex,
    const float* __restrict__ W_kc, const float* __restrict__ fpart_w,
    const float* __restrict__ fpart_b, float* __restrict__ ws)
{
    int t = threadIdx.x, wave = t >> 6, lane = t & 63;
    int blk = blockIdx.x;
    __shared__ float kred[256];
    __shared__ float fwT[64 * 65];
    __shared__ float wkS[64 * 33];

    if (blk < 256) {
        // x[b,d] = su*dot(ex, W_ex[d,:1024]) + (1-su)*dot(ex, W_ex[d,1024:])
        int b = blk >> 3;
        int dbase = (blk & 7) * 8;
        float sub = su[b];
        const float* exb = ex + (size_t)b * NEX;
        float er[16];
        #pragma unroll
        for (int i = 0; i < 16; ++i) er[i] = exb[lane + i * 64];
        #pragma unroll
        for (int p = 0; p < 2; ++p) {
            int d = dbase + wave * 2 + p;
            const float* wr = W_ex + (size_t)d * (2 * NEX);
            float a1 = 0.f, a2 = 0.f;
            #pragma unroll
            for (int i = 0; i < 16; ++i) {
                int k = lane + i * 64;
                a1 = fmaf(er[i], wr[k], a1);
                a2 = fmaf(er[i], wr[NEX + k], a2);
            }
            float v = sub * a1 + (1.0f - sub) * a2;
            #pragma unroll
            for (int off = 32; off; off >>= 1) v += __shfl_down(v, off, 64);
            if (lane == 0) ws[XOFF + b * DH + d] = v;
        }
    } else if (blk < 512) {
        // kci[b, i0..i0+15]: 16 k-slices of 64 per i
        int q = blk - 256;
        int b = q >> 3, i0 = (q & 7) * 16;
        int i = t & 15, ks = t >> 4;
        const float* exb = ex + (size_t)b * NEX;
        const float* eg = ex_graph + i0 + i;
        int kb = ks * 64;
        float a = 0.f;
        #pragma unroll 4
        for (int k = 0; k < 64; ++k)
            a = fmaf(exb[kb + k], eg[(size_t)(kb + k) * NKC], a);
        kred[t] = a;
        __syncthreads();
        if (t < 16) {
            float s = 0.f;
            #pragma unroll
            for (int r = 0; r < 16; ++r) s += kred[r * 16 + t];
            ws[KCIOFF + b * NKC + i0 + t] = s;
        }
    } else {
        // epart[j,d] = sum_c W_kc[c,j]*fpart_w[d,64+c] + fpart_b[d]; 32 j/block
        int eb = blk - 512;
        for (int idx = t; idx < 4096; idx += 256) {
            int d = idx >> 6, c = idx & 63;
            fwT[c * 65 + d] = fpart_w[d * 128 + 64 + c];
        }
        for (int idx = t; idx < 2048; idx += 256) {
            int c = idx >> 5, jl = idx & 31;
            wkS[c * 33 + jl] = W_kc[(size_t)c * NKC + eb * 32 + jl];
        }
        __syncthreads();
        float fb = fpart_b[lane];
        #pragma unroll
        for (int q2 = 0; q2 < 8; ++q2) {
            int jl = wave + 4 * q2;
            float a = fb;
            for (int c = 0; c < 64; ++c)
                a = fmaf(wkS[c * 33 + jl], fwT[c * 65 + lane], a);
            ws[EPOFF + (eb * 32 + jl) * DH + lane] = a;
        }
    }
}

// ---------------------------------------------------------------------------
// k1: tgru + new_h + dpart. 256 blocks (b x 8 i-chunks of 16) x 512 threads
// (8 waves => 2 waves/SIMD). Wave handles 2 i. gi hoisted to a per-block
// pre-phase (i-independent).
// ---------------------------------------------------------------------------
__global__ __launch_bounds__(512) void k1_tgru(
    const float* __restrict__ h, const float* __restrict__ tgru_wih,
    const float* __restrict__ tgru_whh, const float* __restrict__ tgru_bih,
    const float* __restrict__ tgru_bhh, const float* __restrict__ fpart_w,
    float* __restrict__ ws)
{
    int t = threadIdx.x, wave = t >> 6, lane = t & 63;
    int b = blockIdx.x >> 3;
    int i0 = (blockIdx.x & 7) * 16;

    __shared__ float whhT[32 * 193];   // reused for fpart_w^T (64*65)
    __shared__ float wihT[32 * 193];
    __shared__ float ht[16 * DH];
    __shared__ float dlt[16 * DH];
    __shared__ float xs[DH];
    __shared__ float gis[G3];
    __shared__ float bhh3[G3];
    __shared__ float kcis[16];

    const float* hb = h + (size_t)(b * NKC + i0) * DH;
    for (int idx = t; idx < 16 * DH; idx += 512) ht[idx] = hb[idx];
    if (t < DH) xs[t] = ws[XOFF + b * DH + t];
    if (t < G3) bhh3[t] = tgru_bhh[t];
    if (t < 16) kcis[t] = ws[KCIOFF + b * NKC + i0 + t];
    __syncthreads();

    float giA = (t < G3) ? tgru_bih[t] : 0.f;   // per-row gi accumulator
    float ar[2], az[2], an[2];
    #pragma unroll
    for (int m = 0; m < 2; ++m) {
        ar[m] = bhh3[lane]; az[m] = bhh3[64 + lane]; an[m] = bhh3[128 + lane];
    }

    for (int ch = 0; ch < 2; ++ch) {
        __syncthreads();
        for (int idx = t; idx < G3 * 32; idx += 512) {
            int row = idx >> 5, kk = idx & 31;
            whhT[kk * 193 + row] = tgru_whh[row * DH + ch * 32 + kk];
            wihT[kk * 193 + row] = tgru_wih[row * DH + ch * 32 + kk];
        }
        __syncthreads();
        if (t < G3) {   // gi partial: waves 0..2, wave-uniform branch
            for (int kk = 0; kk < 32; ++kk)
                giA = fmaf(wihT[kk * 193 + t], xs[ch * 32 + kk], giA);
        }
        for (int kk = 0; kk < 32; ++kk) {
            float wr = whhT[kk * 193 + lane];
            float wz = whhT[kk * 193 + 64 + lane];
            float wn = whhT[kk * 193 + 128 + lane];
            int k = ch * 32 + kk;
            #pragma unroll
            for (int m = 0; m < 2; ++m) {
                float hk = ht[(wave * 2 + m) * DH + k];   // LDS broadcast
                ar[m] = fmaf(wr, hk, ar[m]);
                az[m] = fmaf(wz, hk, az[m]);
                an[m] = fmaf(wn, hk, an[m]);
            }
        }
    }
    if (t < G3) gis[t] = giA;
    __syncthreads();
    // GRU epilogue per i
    #pragma unroll
    for (int m = 0; m < 2; ++m) {
        int il = wave * 2 + m;
        float hval = ht[il * DH + lane];
        float r = sigf(gis[lane] + ar[m]);
        float z = sigf(gis[64 + lane] + az[m]);
        float n = tanhf(gis[128 + lane] + r * an[m]);
        float th = (1.0f - z) * n + z * hval;
        float kv = kcis[il];
        float nh = (1.0f - kv) * hval + kv * th;
        ws[NHOFF + (size_t)(b * NKC + i0 + il) * DH + lane] = nh;
        dlt[il * DH + lane] = kv * (th - hval);   // delta_h
    }
    __syncthreads();
    // dpart = delta_h @ fpart_w[:, :64].T ; fpart_w^T staged (stride 65)
    for (int idx = t; idx < 4096; idx += 512) {
        int d = idx >> 6, k = idx & 63;
        whhT[k * 65 + d] = fpart_w[d * 128 + k];
    }
    __syncthreads();
    float acc[2];
    acc[0] = 0.f; acc[1] = 0.f;
    for (int k = 0; k < 64; ++k) {
        float w = whhT[k * 65 + lane];
        #pragma unroll
        for (int m = 0; m < 2; ++m)
            acc[m] = fmaf(dlt[(wave * 2 + m) * DH + k], w, acc[m]);
    }
    #pragma unroll
    for (int m = 0; m < 2; ++m)
        ws[DPOFF + (size_t)(b * NKC + i0 + wave * 2 + m) * DH + lane] = acc[m];
}

// ---------------------------------------------------------------------------
// kB: partj + outj + kcj + ugru + h_out. 256 blocks (b x 8 j-chunks of 16)
// x 512 threads (2 waves/SIMD). Wave handles 2 j.
// ---------------------------------------------------------------------------
__global__ __launch_bounds__(512) void kB_update(
    const float* __restrict__ kc_gamma,
    const float* __restrict__ ulin_w, const float* __restrict__ ulin_b,
    const float* __restrict__ ugru_wih, const float* __restrict__ ugru_whh,
    const float* __restrict__ ugru_bih, const float* __restrict__ ugru_bhh,
    float* __restrict__ ws, float* __restrict__ out)
{
    int t = threadIdx.x, wave = t >> 6, lane = t & 63;
    int b = blockIdx.x >> 3;
    int j0 = (blockIdx.x & 7) * 16;

    __shared__ float scratch[12352];  // a: dpart|wj|ep; b: ulin^T; c: wih^T+whh^T
    __shared__ float pjS[16 * DH];
    __shared__ float outjS[16 * DH];
    __shared__ float newhS[16 * DH];
    __shared__ float kcis[NKC];
    __shared__ float kcjS[16];
    __shared__ float bihS[G3];
    __shared__ float bhhS[G3];

    float* dpartS = scratch;           // 8192  [i*64+d]
    float* wjS    = scratch + 8192;    // 2048  [i*16+jl]
    float* epS    = scratch + 10240;   // 1024  [jl*64+d]

    const float* dp = ws + DPOFF + (size_t)b * NKC * DH;
    for (int idx = t; idx < NKC * DH; idx += 512) dpartS[idx] = dp[idx];
    if (t < NKC) kcis[t] = ws[KCIOFF + b * NKC + t];
    for (int idx = t; idx < 16 * DH; idx += 512) {
        epS[idx]   = ws[EPOFF + j0 * DH + idx];
        newhS[idx] = ws[NHOFF + (size_t)(b * NKC + j0) * DH + idx];
    }
    if (t < G3) { bihS[t] = ugru_bih[t]; bhhS[t] = ugru_bhh[t]; }
    __syncthreads();
    // wj[i,jl] = kci[i] * sigmoid(kc_gamma[i, j0+jl])
    for (int idx = t; idx < 2048; idx += 512) {
        int i = idx >> 4, jl = idx & 15;
        wjS[idx] = kcis[i] * sigf(kc_gamma[i * NKC + j0 + jl]);
    }
    __syncthreads();
    if (t < 16) {  // kcj[jl] = sum_i wj[i,jl]
        float s = 0.f;
        for (int i = 0; i < NKC; ++i) s += wjS[i * 16 + t];
        kcjS[t] = s;
    }
    // phase a: partj — i-loop shared across 2 j per wave
    float ep[2], pa[2];
    #pragma unroll
    for (int m = 0; m < 2; ++m) { ep[m] = epS[(wave * 2 + m) * DH + lane]; pa[m] = 0.f; }
    for (int i = 0; i < NKC; ++i) {
        float dv = dpartS[i * DH + lane];
        #pragma unroll
        for (int m = 0; m < 2; ++m) {
            float pre = fmaxf(dv + ep[m], 0.f);
            pa[m] = fmaf(pre, wjS[i * 16 + wave * 2 + m], pa[m]);
        }
    }
    #pragma unroll
    for (int m = 0; m < 2; ++m) pjS[(wave * 2 + m) * DH + lane] = pa[m];
    __syncthreads();
    // phase b: outj = relu(partj @ ulin_w.T + b)
    float* ulT = scratch;  // 64*65
    for (int idx = t; idx < 4096; idx += 512) {
        int d2 = idx >> 6, k = idx & 63;
        ulT[k * 65 + d2] = ulin_w[d2 * DH + k];
    }
    float ulb = ulin_b[lane];
    __syncthreads();
    #pragma unroll
    for (int m = 0; m < 2; ++m) {
        int jl = wave * 2 + m;
        float a = ulb;
        for (int k = 0; k < DH; ++k) a = fmaf(pjS[jl * DH + k], ulT[k * 65 + lane], a);
        outjS[jl * DH + lane] = fmaxf(a, 0.f);
    }
    // phase c: ugru — both weight matrices k-chunk staged
    float* wihT = scratch;           // 32*193
    float* whhT = scratch + 6176;    // 32*193
    float gir[2], giz[2], gin[2], ghr[2], ghz[2], ghn[2];
    #pragma unroll
    for (int m = 0; m < 2; ++m) { gir[m] = giz[m] = gin[m] = ghr[m] = ghz[m] = ghn[m] = 0.f; }
    for (int ch = 0; ch < 2; ++ch) {
        __syncthreads();   // also covers phase-b reads of ulT before overwrite
        for (int idx = t; idx < G3 * 32; idx += 512) {
            int row = idx >> 5, kk = idx & 31;
            wihT[kk * 193 + row] = ugru_wih[row * DH + ch * 32 + kk];
            whhT[kk * 193 + row] = ugru_whh[row * DH + ch * 32 + kk];
        }
        __syncthreads();
        for (int kk = 0; kk < 32; ++kk) {
            float wir = wihT[kk * 193 + lane];
            float wiz = wihT[kk * 193 + 64 + lane];
            float win = wihT[kk * 193 + 128 + lane];
            float wwr = whhT[kk * 193 + lane];
            float wwz = whhT[kk * 193 + 64 + lane];
            float wwn = whhT[kk * 193 + 128 + lane];
            int k = ch * 32 + kk;
            #pragma unroll
            for (int m = 0; m < 2; ++m) {
                int jl = wave * 2 + m;
                float ov = outjS[jl * DH + k];
                float nv = newhS[jl * DH + k];
                gir[m] = fmaf(wir, ov, gir[m]);
                giz[m] = fmaf(wiz, ov, giz[m]);
                gin[m] = fmaf(win, ov, gin[m]);
                ghr[m] = fmaf(wwr, nv, ghr[m]);
                ghz[m] = fmaf(wwz, nv, ghz[m]);
                ghn[m] = fmaf(wwn, nv, ghn[m]);
            }
        }
    }
    #pragma unroll
    for (int m = 0; m < 2; ++m) {
        int jl = wave * 2 + m;
        float r = sigf(gir[m] + bihS[lane] + ghr[m] + bhhS[lane]);
        float z = sigf(giz[m] + bihS[64 + lane] + ghz[m] + bhhS[64 + lane]);
        float n = tanhf(gin[m] + bihS[128 + lane] + r * (ghn[m] + bhhS[128 + lane]));
        float nh = newhS[jl * DH + lane];
        float uh = (1.0f - z) * n + z * nh;
        float kj = kcjS[jl];
        out[(size_t)(b * NKC + j0 + jl) * DH + lane] = (1.0f - kj) * nh + kj * uh;
    }
}

extern "C" void kernel_launch(void* const* d_in, const int* in_sizes, int n_in,
                              void* d_out, int out_size, void* d_ws, size_t ws_size,
                              hipStream_t stream) {
    const float* h        = (const float*)d_in[0];
    const float* ex       = (const float*)d_in[1];
    const float* su       = (const float*)d_in[2];
    const float* ex_graph = (const float*)d_in[3];
    const float* kc_gamma = (const float*)d_in[4];
    const float* W_ex     = (const float*)d_in[5];
    const float* W_kc     = (const float*)d_in[6];
    const float* tgru_wih = (const float*)d_in[7];
    const float* tgru_whh = (const float*)d_in[8];
    const float* tgru_bih = (const float*)d_in[9];
    const float* tgru_bhh = (const float*)d_in[10];
    const float* fpart_w  = (const float*)d_in[11];
    const float* fpart_b  = (const float*)d_in[12];
    const float* ulin_w   = (const float*)d_in[13];
    const float* ulin_b   = (const float*)d_in[14];
    const float* ugru_wih = (const float*)d_in[15];
    const float* ugru_whh = (const float*)d_in[16];
    const float* ugru_bih = (const float*)d_in[17];
    const float* ugru_bhh = (const float*)d_in[18];
    float* ws  = (float*)d_ws;
    float* out = (float*)d_out;

    hipLaunchKernelGGL(k0_prep, dim3(516), dim3(256), 0, stream,
                       ex, su, ex_graph, W_ex, W_kc, fpart_w, fpart_b, ws);
    hipLaunchKernelGGL(k1_tgru, dim3(256), dim3(512), 0, stream,
                       h, tgru_wih, tgru_whh, tgru_bih, tgru_bhh, fpart_w, ws);
    hipLaunchKernelGGL(kB_update, dim3(256), dim3(512), 0, stream,
                       kc_gamma, ulin_w, ulin_b,
                       ugru_wih, ugru_whh, ugru_bih, ugru_bhh, ws, out);
}